// Round 1
// baseline (3243.656 us; speedup 1.0000x reference)
//
#include <hip/hip_runtime.h>
#include <hip/hip_bf16.h>

#define NN 100000
#define EE 400000
#define GG 4096
#define DD 128
#define ATOM_DIM 101
#define BOND_DIM 11

// ---------------- index dtype detection (int32 vs int64) ----------------
__global__ void detect64_kernel(const void* ei, int npairs, int* flag) {
    const int* p = (const int*)ei;
    int any = 0;
    for (int i = 1; i < 2 * npairs; i += 2) any |= p[i];
    *flag = (any == 0) ? 1 : 0;   // all hi-words zero => int64
}

__device__ __forceinline__ int getIdx(const void* p, long i, int is64) {
    if (is64) return (int)(((const long long*)p)[i]);
    return ((const int*)p)[i];
}

// ---------------- fused fp32 GEMM ----------------
// C[M,Cout] = (transform(A) [+ Agg]) @ W[K,Cout] + bias
// transform(v, col k) = relu_in? max(v*sc[k]+sh[k],0) : v*sc[k]+sh[k]; sc==null => identity
__global__ __launch_bounds__(256) void gemm_fused(
    const float* __restrict__ A, int lda,
    const float* __restrict__ Agg,
    const float* __restrict__ sc, const float* __restrict__ sh, int relu_in,
    const float* __restrict__ W, const float* __restrict__ bias,
    float* __restrict__ C, int M, int K, int Cout)
{
    __shared__ float As[32][68];   // [k][m], padded: conflict-free + 16B aligned rows
    __shared__ float Bs[32][64];   // [k][n]
    const int tid = threadIdx.x;
    const int tx = tid & 15, ty = tid >> 4;
    const int row0 = blockIdx.x * 64;
    const int col0 = blockIdx.y * 64;
    float acc[4][4] = {};
    const int nk = (K + 31) >> 5;
    for (int kt = 0; kt < nk; ++kt) {
        const int k0 = kt << 5;
        #pragma unroll
        for (int i = 0; i < 8; ++i) {           // A tile 64x32
            int e = i * 256 + tid;
            int r = e >> 5, k = e & 31;
            int gr = row0 + r, gk = k0 + k;
            float v = 0.f;
            if (gr < M && gk < K) {
                v = A[(long)gr * lda + gk];
                if (sc) v = v * sc[gk] + sh[gk];
                if (relu_in) v = fmaxf(v, 0.f);
                if (Agg) v += Agg[(long)gr * lda + gk];
            }
            As[k][r] = v;
        }
        #pragma unroll
        for (int i = 0; i < 8; ++i) {           // B tile 32x64
            int e = i * 256 + tid;
            int kk = e >> 6, c = e & 63;
            int gk = k0 + kk, gc = col0 + c;
            Bs[kk][c] = (gk < K) ? W[(long)gk * Cout + gc] : 0.f;
        }
        __syncthreads();
        #pragma unroll
        for (int k = 0; k < 32; ++k) {
            float4 a4 = *(const float4*)&As[k][ty * 4];
            float4 b4 = *(const float4*)&Bs[k][tx * 4];
            float av[4] = {a4.x, a4.y, a4.z, a4.w};
            float bv[4] = {b4.x, b4.y, b4.z, b4.w};
            #pragma unroll
            for (int i = 0; i < 4; ++i)
                #pragma unroll
                for (int j = 0; j < 4; ++j)
                    acc[i][j] += av[i] * bv[j];
        }
        __syncthreads();
    }
    const int gc0 = col0 + tx * 4;
    float4 bb = *(const float4*)&bias[gc0];
    #pragma unroll
    for (int i = 0; i < 4; ++i) {
        int gr = row0 + ty * 4 + i;
        if (gr >= M) continue;
        float4 o;
        o.x = acc[i][0] + bb.x; o.y = acc[i][1] + bb.y;
        o.z = acc[i][2] + bb.z; o.w = acc[i][3] + bb.w;
        *(float4*)&C[(long)gr * Cout + gc0] = o;
    }
}

// ---------------- edge message + scatter-add ----------------
__global__ __launch_bounds__(256) void msg_kernel(
    const float* __restrict__ hraw,
    const float* __restrict__ sc, const float* __restrict__ sh, int relu_in,
    const void* __restrict__ eidx, const int* __restrict__ flag,
    const float* __restrict__ ea,   // [E,11]
    const float* __restrict__ bw,   // [11,128]
    const float* __restrict__ bb,   // [128]
    float* __restrict__ agg, int E)
{
    __shared__ float sbw[BOND_DIM * DD];
    __shared__ float sbb[DD];
    const int t = threadIdx.x;
    const int d = t & 127;
    const int sub = t >> 7;   // 0 or 1: two edges per block-iter
    for (int i = t; i < BOND_DIM * DD; i += 256) sbw[i] = bw[i];
    if (t < DD) sbb[t] = bb[t];
    const int is64 = *flag;
    const float scv = sc ? sc[d] : 1.f;
    const float shv = sc ? sh[d] : 0.f;
    __syncthreads();
    for (int e0 = blockIdx.x * 2; e0 < E; e0 += gridDim.x * 2) {
        int e = e0 + sub;
        if (e >= E) continue;
        int s  = getIdx(eidx, e, is64);
        int dn = getIdx(eidx, (long)E + e, is64);
        float x = sbb[d];
        #pragma unroll
        for (int k = 0; k < BOND_DIM; ++k)
            x += ea[(long)e * BOND_DIM + k] * sbw[k * DD + d];
        float hv = hraw[(long)s * DD + d];
        hv = hv * scv + shv;
        if (relu_in) hv = fmaxf(hv, 0.f);
        float m = fmaxf(hv + x, 0.f);
        unsafeAtomicAdd(&agg[(long)dn * DD + d], m);
    }
}

// ---------------- BN column stats ----------------
__global__ void col_stats(const float* __restrict__ X, int M, int C, float* __restrict__ stat)
{
    const int c = threadIdx.x;     // blockDim.x == C
    float s = 0.f, q = 0.f;
    for (int r = blockIdx.x; r < M; r += gridDim.x) {
        float v = X[(long)r * C + c];
        s += v; q += v * v;
    }
    unsafeAtomicAdd(&stat[c], s);
    unsafeAtomicAdd(&stat[C + c], q);
}

__global__ void bn_finalize(const float* __restrict__ stat,
                            const float* __restrict__ gamma, const float* __restrict__ beta,
                            int C, float invN, float* __restrict__ sc, float* __restrict__ sh)
{
    int c = threadIdx.x;
    if (c >= C) return;
    float m = stat[c] * invN;
    float v = stat[C + c] * invN - m * m;
    float s = gamma[c] * rsqrtf(v + 1e-5f);
    sc[c] = s;
    sh[c] = beta[c] - m * s;
}

// ---------------- pooling (mean per graph; batch sorted) ----------------
__global__ __launch_bounds__(128) void pool_kernel(
    const float* __restrict__ hraw,
    const float* __restrict__ sc, const float* __restrict__ sh,
    const void* __restrict__ batchp, const int* __restrict__ flag,
    int Nn, float* __restrict__ out)
{
    const int g = blockIdx.x;
    const int t = threadIdx.x;
    const int is64 = *flag;
    int lo = 0, hi = Nn;
    while (lo < hi) { int mid = (lo + hi) >> 1; if (getIdx(batchp, mid, is64) < g) lo = mid + 1; else hi = mid; }
    const int s0 = lo;
    hi = Nn;
    while (lo < hi) { int mid = (lo + hi) >> 1; if (getIdx(batchp, mid, is64) < g + 1) lo = mid + 1; else hi = mid; }
    const int s1 = lo;
    float acc = 0.f;
    for (int r = s0; r < s1; ++r) acc += hraw[(long)r * DD + t];
    const int cnt = s1 - s0;
    float v = 0.f;
    if (cnt > 0) v = (acc / (float)cnt) * sc[t] + sh[t];
    out[(long)g * DD + t] = v;
}

// ---------------- launch ----------------
extern "C" void kernel_launch(void* const* d_in, const int* in_sizes, int n_in,
                              void* d_out, int out_size, void* d_ws, size_t ws_size,
                              hipStream_t stream)
{
    const float* x     = (const float*)d_in[0];
    const float* ea    = (const float*)d_in[1];
    const float* embW  = (const float*)d_in[2];
    const float* embB  = (const float*)d_in[3];
    const float* bondW = (const float*)d_in[4];
    const float* bondB = (const float*)d_in[5];
    const float* W1    = (const float*)d_in[6];
    const float* b1    = (const float*)d_in[7];
    const float* g1    = (const float*)d_in[8];
    const float* be1   = (const float*)d_in[9];
    const float* W2    = (const float*)d_in[10];
    const float* b2    = (const float*)d_in[11];
    const float* gout  = (const float*)d_in[12];
    const float* bout  = (const float*)d_in[13];
    const void*  eidx  = d_in[14];
    const void*  batch = d_in[15];

    float* out = (float*)d_out;

    float* hraw = (float*)d_ws;                 // [N,128]
    float* agg  = hraw + (long)NN * DD;         // [N,128]
    float* z1   = agg  + (long)NN * DD;         // [N,256]
    float* stat = z1   + (long)NN * 256;        // 512
    float* sc1  = stat + 512;                   // 256
    float* sh1  = sc1 + 256;                    // 256
    float* sc2  = sh1 + 256;                    // 128
    float* sh2  = sc2 + 128;                    // 128
    int*   flag = (int*)(sh2 + 128);

    detect64_kernel<<<1, 1, 0, stream>>>(eidx, 256, flag);

    const int mtiles = (NN + 63) / 64;

    // h0 = x @ embW + embB
    gemm_fused<<<dim3(mtiles, 2), 256, 0, stream>>>(
        x, ATOM_DIM, nullptr, nullptr, nullptr, 0, embW, embB, hraw, NN, ATOM_DIM, DD);

    const float* scin = nullptr;
    const float* shin = nullptr;
    int relu_in = 0;

    for (int i = 0; i < 3; ++i) {
        hipMemsetAsync(agg, 0, (size_t)NN * DD * sizeof(float), stream);
        msg_kernel<<<4096, 256, 0, stream>>>(
            hraw, scin, shin, relu_in, eidx, flag, ea,
            bondW + (long)i * BOND_DIM * DD, bondB + (long)i * DD, agg, EE);

        // z1 = (bn(hraw)[relu] + agg) @ W1 + b1
        gemm_fused<<<dim3(mtiles, 4), 256, 0, stream>>>(
            hraw, DD, agg, scin, shin, relu_in,
            W1 + (long)i * DD * 256, b1 + (long)i * 256, z1, NN, DD, 256);

        hipMemsetAsync(stat, 0, 512 * sizeof(float), stream);
        col_stats<<<512, 256, 0, stream>>>(z1, NN, 256, stat);
        bn_finalize<<<1, 256, 0, stream>>>(stat, g1 + (long)i * 256, be1 + (long)i * 256,
                                           256, 1.f / NN, sc1, sh1);

        // hraw = relu(bn1(z1)) @ W2 + b2
        gemm_fused<<<dim3(mtiles, 2), 256, 0, stream>>>(
            z1, 256, nullptr, sc1, sh1, 1,
            W2 + (long)i * 256 * DD, b2 + (long)i * DD, hraw, NN, 256, DD);

        hipMemsetAsync(stat, 0, 256 * sizeof(float), stream);
        col_stats<<<512, 128, 0, stream>>>(hraw, NN, DD, stat);
        bn_finalize<<<1, 128, 0, stream>>>(stat, gout + (long)i * DD, bout + (long)i * DD,
                                           DD, 1.f / NN, sc2, sh2);

        scin = sc2; shin = sh2; relu_in = 1;   // consumed with relu by next layer
    }

    // mean pool + final BN (linear, applied post-mean); empty graphs -> 0
    pool_kernel<<<GG, DD, 0, stream>>>(hraw, sc2, sh2, batch, flag, NN, out);
}

// Round 2
// 1270.893 us; speedup vs baseline: 2.5523x; 2.5523x over previous
//
#include <hip/hip_runtime.h>
#include <hip/hip_bf16.h>

#define NN 100000
#define EE 400000
#define GG 4096
#define DD 128
#define ATOM_DIM 101
#define BOND_DIM 11

typedef __attribute__((ext_vector_type(8))) short bf16x8;
typedef __attribute__((ext_vector_type(4))) float f32x4;
typedef __attribute__((ext_vector_type(4))) short short4v;

__device__ __forceinline__ float b2f(short s) {
    unsigned u = ((unsigned)(unsigned short)s) << 16;
    float f; __builtin_memcpy(&f, &u, 4); return f;
}
__device__ __forceinline__ unsigned short f2b(float f) {
    unsigned u; __builtin_memcpy(&u, &f, 4);
    u += 0x7FFFu + ((u >> 16) & 1u);          // RNE
    return (unsigned short)(u >> 16);
}

// ---------------- index dtype detection (int32 vs int64) ----------------
__global__ void detect64_kernel(const void* ei, int npairs, int* flag) {
    const int* p = (const int*)ei;
    int any = 0;
    for (int i = 1; i < 2 * npairs; i += 2) any |= p[i];
    *flag = (any == 0) ? 1 : 0;
}
__device__ __forceinline__ int getIdx(const void* p, long i, int is64) {
    if (is64) return (int)(((const long long*)p)[i]);
    return ((const int*)p)[i];
}

// ---------------- weight pre-pack: W[K][N] f32 -> Wf[ks][f][lane][8] bf16 ----
__global__ void pack_w(const float* __restrict__ W, unsigned short* __restrict__ Wf,
                       int Kact, int N, int KSTEPS) {
    int idx = blockIdx.x * blockDim.x + threadIdx.x;
    int NF = N >> 4;
    int total = KSTEPS * NF * 64;
    if (idx >= total) return;
    int l = idx & 63;
    int f = (idx >> 6) % NF;
    int ks = idx / (64 * NF);
    int col = f * 16 + (l & 15);
    int k0 = ks * 32 + (l >> 4) * 8;
    bf16x8 v;
    #pragma unroll
    for (int j = 0; j < 8; ++j) {
        int k = k0 + j;
        v[j] = (k < Kact) ? (short)f2b(W[(long)k * N + col]) : (short)0;
    }
    *(bf16x8*)(Wf + (long)idx * 8) = v;
}

// ---------------- x f32 [N,101] -> xb bf16 [N,128] zero-padded ----------------
__global__ void pack_x(const float* __restrict__ x, unsigned short* __restrict__ xb) {
    const long total = (long)NN * 128;
    for (long i = (long)blockIdx.x * blockDim.x + threadIdx.x; i < total;
         i += (long)gridDim.x * blockDim.x) {
        int col = (int)(i & 127);
        long row = i >> 7;
        xb[i] = (col < ATOM_DIM) ? f2b(x[row * ATOM_DIM + col]) : (unsigned short)0;
    }
}

// ---------------- t = bf16(relu(h*sc+sh)) ----------------
__global__ __launch_bounds__(256) void transform_kernel(
    const float* __restrict__ h, const float* __restrict__ sc,
    const float* __restrict__ sh, unsigned short* __restrict__ t) {
    long i = (long)blockIdx.x * blockDim.x + threadIdx.x;
    long base = i * 4;
    if (base >= (long)NN * DD) return;
    int col = (int)(base & 127);
    f32x4 hv = *(const f32x4*)(h + base);
    f32x4 s = *(const f32x4*)(sc + col);
    f32x4 b = *(const f32x4*)(sh + col);
    short4v o;
    o[0] = (short)f2b(fmaxf(hv.x * s.x + b.x, 0.f));
    o[1] = (short)f2b(fmaxf(hv.y * s.y + b.y, 0.f));
    o[2] = (short)f2b(fmaxf(hv.z * s.z + b.z, 0.f));
    o[3] = (short)f2b(fmaxf(hv.w * s.w + b.w, 0.f));
    *(short4v*)(t + base) = o;
}

// ---------------- MFMA GEMM, fused transform + stats ----------------
// MODE 0: A plain bf16.  MODE 1: A + agg (f32).  MODE 2: relu(A*sc+sh).
template<int NF, int KSTEPS, int MODE, bool OUT_BF16, bool STATS>
__global__ __launch_bounds__(256) void gemm_mfma(
    const unsigned short* __restrict__ A,   // [M][K] bf16
    const float* __restrict__ agg,
    const float* __restrict__ sc, const float* __restrict__ sh,
    const unsigned short* __restrict__ Wf,  // packed [KSTEPS][NF][64][8]
    const float* __restrict__ bias,         // [NF*16]
    void* __restrict__ outp,
    float* __restrict__ stat,               // [2*NF*16]
    int M)
{
    constexpr int K = KSTEPS * 32;
    constexpr int NC = NF * 16;
    __shared__ float s_sum[NC];
    __shared__ float s_sq[NC];
    const int tid = threadIdx.x;
    const int wave = tid >> 6, l = tid & 63;
    const int r0 = blockIdx.x * 64 + wave * 16;
    const int rr = r0 + (l & 15);
    const int rc = rr < M ? rr : M - 1;
    const int kg = (l >> 4) * 8;

    if (STATS) {
        for (int i = tid; i < NC; i += 256) { s_sum[i] = 0.f; s_sq[i] = 0.f; }
        __syncthreads();
    }

    bf16x8 af[KSTEPS];
    #pragma unroll
    for (int ks = 0; ks < KSTEPS; ++ks) {
        const unsigned short* ap = A + (long)rc * K + ks * 32 + kg;
        bf16x8 a = *(const bf16x8*)ap;
        if (MODE == 1) {
            const float* gp = agg + (long)rc * K + ks * 32 + kg;
            f32x4 g0 = *(const f32x4*)gp, g1 = *(const f32x4*)(gp + 4);
            float gv[8] = {g0.x, g0.y, g0.z, g0.w, g1.x, g1.y, g1.z, g1.w};
            #pragma unroll
            for (int j = 0; j < 8; ++j) a[j] = (short)f2b(b2f(a[j]) + gv[j]);
        } else if (MODE == 2) {
            const float* scp = sc + ks * 32 + kg;
            const float* shp = sh + ks * 32 + kg;
            f32x4 s0 = *(const f32x4*)scp, s1 = *(const f32x4*)(scp + 4);
            f32x4 h0 = *(const f32x4*)shp, h1 = *(const f32x4*)(shp + 4);
            float sv[8] = {s0.x, s0.y, s0.z, s0.w, s1.x, s1.y, s1.z, s1.w};
            float hv[8] = {h0.x, h0.y, h0.z, h0.w, h1.x, h1.y, h1.z, h1.w};
            #pragma unroll
            for (int j = 0; j < 8; ++j) {
                float v = fmaxf(b2f(a[j]) * sv[j] + hv[j], 0.f);
                a[j] = (short)f2b(v);
            }
        }
        af[ks] = a;
    }

    f32x4 acc[NF];
    #pragma unroll
    for (int f = 0; f < NF; ++f) acc[f] = (f32x4){0.f, 0.f, 0.f, 0.f};

    const bf16x8* wp = (const bf16x8*)Wf;
    #pragma unroll
    for (int ks = 0; ks < KSTEPS; ++ks) {
        #pragma unroll
        for (int f = 0; f < NF; ++f) {
            bf16x8 b = wp[(ks * NF + f) * 64 + l];
            acc[f] = __builtin_amdgcn_mfma_f32_16x16x32_bf16(af[ks], b, acc[f], 0, 0, 0);
        }
    }

    #pragma unroll
    for (int f = 0; f < NF; ++f) {
        const int col = f * 16 + (l & 15);
        const float bb = bias[col];
        float sum = 0.f, sq = 0.f;
        #pragma unroll
        for (int j = 0; j < 4; ++j) {
            int r = r0 + (l >> 4) * 4 + j;
            if (r < M) {
                float v = acc[f][j] + bb;
                if (OUT_BF16) ((unsigned short*)outp)[(long)r * NC + col] = f2b(v);
                else          ((float*)outp)[(long)r * NC + col] = v;
                sum += v; sq += v * v;
            }
        }
        if (STATS) {
            atomicAdd(&s_sum[col], sum);
            atomicAdd(&s_sq[col], sq);
        }
    }
    if (STATS) {
        __syncthreads();
        if (tid < NC) {
            unsafeAtomicAdd(&stat[tid], s_sum[tid]);
            unsafeAtomicAdd(&stat[NC + tid], s_sq[tid]);
        }
    }
}

// ---------------- edge message + scatter-add (bf16 gather) ----------------
__global__ __launch_bounds__(256) void msg_kernel(
    const unsigned short* __restrict__ t,
    const void* __restrict__ eidx, const int* __restrict__ flag,
    const float* __restrict__ ea, const float* __restrict__ bw,
    const float* __restrict__ bb, float* __restrict__ agg, int E)
{
    __shared__ float sbw[BOND_DIM * DD];
    __shared__ float sbb[DD];
    const int tid = threadIdx.x;
    const int d = tid & 127;
    const int sub = tid >> 7;
    for (int i = tid; i < BOND_DIM * DD; i += 256) sbw[i] = bw[i];
    if (tid < DD) sbb[tid] = bb[tid];
    const int is64 = *flag;
    __syncthreads();
    for (long e = (long)blockIdx.x * 2 + sub; e < E; e += (long)gridDim.x * 2) {
        int s  = getIdx(eidx, e, is64);
        int dn = getIdx(eidx, (long)E + e, is64);
        float x = sbb[d];
        #pragma unroll
        for (int k = 0; k < BOND_DIM; ++k)
            x += ea[e * BOND_DIM + k] * sbw[k * DD + d];
        float hv = b2f(t[(long)s * DD + d]);
        float m = fmaxf(hv + x, 0.f);
        unsafeAtomicAdd(&agg[(long)dn * DD + d], m);
    }
}

// ---------------- BN finalize ----------------
__global__ void bn_finalize(const float* __restrict__ stat,
                            const float* __restrict__ gamma, const float* __restrict__ beta,
                            int C, float invN, float* __restrict__ sc, float* __restrict__ sh)
{
    int c = threadIdx.x;
    if (c >= C) return;
    float m = stat[c] * invN;
    float v = stat[C + c] * invN - m * m;
    float s = gamma[c] * rsqrtf(v + 1e-5f);
    sc[c] = s;
    sh[c] = beta[c] - m * s;
}

// ---------------- pooling ----------------
__global__ __launch_bounds__(128) void pool_kernel(
    const float* __restrict__ hraw,
    const float* __restrict__ sc, const float* __restrict__ sh,
    const void* __restrict__ batchp, const int* __restrict__ flag,
    int Nn, float* __restrict__ out)
{
    const int g = blockIdx.x;
    const int t = threadIdx.x;
    const int is64 = *flag;
    int lo = 0, hi = Nn;
    while (lo < hi) { int mid = (lo + hi) >> 1; if (getIdx(batchp, mid, is64) < g) lo = mid + 1; else hi = mid; }
    const int s0 = lo;
    hi = Nn;
    while (lo < hi) { int mid = (lo + hi) >> 1; if (getIdx(batchp, mid, is64) < g + 1) lo = mid + 1; else hi = mid; }
    const int s1 = lo;
    float acc = 0.f;
    for (int r = s0; r < s1; ++r) acc += hraw[(long)r * DD + t];
    const int cnt = s1 - s0;
    float v = 0.f;
    if (cnt > 0) v = (acc / (float)cnt) * sc[t] + sh[t];
    out[(long)g * DD + t] = v;
}

// ---------------- launch ----------------
extern "C" void kernel_launch(void* const* d_in, const int* in_sizes, int n_in,
                              void* d_out, int out_size, void* d_ws, size_t ws_size,
                              hipStream_t stream)
{
    const float* x     = (const float*)d_in[0];
    const float* ea    = (const float*)d_in[1];
    const float* embW  = (const float*)d_in[2];
    const float* embB  = (const float*)d_in[3];
    const float* bondW = (const float*)d_in[4];
    const float* bondB = (const float*)d_in[5];
    const float* W1    = (const float*)d_in[6];
    const float* b1    = (const float*)d_in[7];
    const float* g1    = (const float*)d_in[8];
    const float* be1   = (const float*)d_in[9];
    const float* W2    = (const float*)d_in[10];
    const float* b2    = (const float*)d_in[11];
    const float* gout  = (const float*)d_in[12];
    const float* bout  = (const float*)d_in[13];
    const void*  eidx  = d_in[14];
    const void*  batch = d_in[15];
    float* out = (float*)d_out;

    char* w = (char*)d_ws;
    unsigned short* t   = (unsigned short*)w;             w += (long)NN * DD * 2;      // 25.6MB
    unsigned short* z1  = (unsigned short*)w;             w += (long)NN * 256 * 2;     // 51.2MB
    unsigned short* xb  = z1;  // alias: xb consumed (emb gemm) before z1 is written
    float* agg  = (float*)w;                              w += (long)NN * DD * 4;      // 51.2MB
    float* h    = (float*)w;                              w += (long)NN * DD * 4;      // 51.2MB
    float* stat = (float*)w;                              w += 768 * 4;
    float* sc1  = (float*)w;                              w += 256 * 4;
    float* sh1  = (float*)w;                              w += 256 * 4;
    float* sc2  = (float*)w;                              w += 128 * 4;
    float* sh2  = (float*)w;                              w += 128 * 4;
    unsigned short* embWf = (unsigned short*)w;           w += 4 * 8  * 64 * 8 * 2;    // 32KB
    unsigned short* W1f   = (unsigned short*)w;           w += 3L * 4 * 16 * 64 * 8 * 2; // 192KB
    unsigned short* W2f   = (unsigned short*)w;           w += 3L * 8 * 8  * 64 * 8 * 2; // 192KB
    int* flag = (int*)w;

    detect64_kernel<<<1, 1, 0, stream>>>(eidx, 256, flag);

    // pre-pack
    pack_x<<<4096, 256, 0, stream>>>(x, xb);
    pack_w<<<8, 256, 0, stream>>>(embW, embWf, ATOM_DIM, 128, 4);
    for (int i = 0; i < 3; ++i) {
        pack_w<<<16, 256, 0, stream>>>(W1 + (long)i * 128 * 256, W1f + (long)i * 4 * 16 * 64 * 8, 128, 256, 4);
        pack_w<<<16, 256, 0, stream>>>(W2 + (long)i * 256 * 128, W2f + (long)i * 8 * 8 * 64 * 8, 256, 128, 8);
    }

    const int gblocks = (NN + 63) / 64;

    // t = bf16(x @ embW + embB)
    gemm_mfma<8, 4, 0, true, false><<<gblocks, 256, 0, stream>>>(
        xb, nullptr, nullptr, nullptr, embWf, embB, t, nullptr, NN);

    for (int i = 0; i < 3; ++i) {
        hipMemsetAsync(agg, 0, (size_t)NN * DD * sizeof(float), stream);
        msg_kernel<<<4096, 256, 0, stream>>>(
            t, eidx, flag, ea, bondW + (long)i * BOND_DIM * DD, bondB + (long)i * DD, agg, EE);

        hipMemsetAsync(stat, 0, 768 * sizeof(float), stream);

        // z1 = (t + agg) @ W1 + b1   [stats -> stat[0:512]]
        gemm_mfma<16, 4, 1, true, true><<<gblocks, 256, 0, stream>>>(
            t, agg, nullptr, nullptr, W1f + (long)i * 4 * 16 * 64 * 8,
            b1 + (long)i * 256, z1, stat, NN);
        bn_finalize<<<1, 256, 0, stream>>>(stat, g1 + (long)i * 256, be1 + (long)i * 256,
                                           256, 1.f / NN, sc1, sh1);

        // h = relu(bn(z1)) @ W2 + b2   [stats -> stat[512:768]]
        gemm_mfma<8, 8, 2, false, true><<<gblocks, 256, 0, stream>>>(
            z1, nullptr, sc1, sh1, W2f + (long)i * 8 * 8 * 64 * 8,
            b2 + (long)i * DD, h, stat + 512, NN);
        bn_finalize<<<1, 128, 0, stream>>>(stat + 512, gout + (long)i * DD, bout + (long)i * DD,
                                           DD, 1.f / NN, sc2, sh2);

        if (i < 2)
            transform_kernel<<<(int)(((long)NN * DD / 4 + 255) / 256), 256, 0, stream>>>(h, sc2, sh2, t);
    }

    pool_kernel<<<GG, DD, 0, stream>>>(h, sc2, sh2, batch, flag, NN, out);
}

// Round 3
// 996.153 us; speedup vs baseline: 3.2562x; 1.2758x over previous
//
#include <hip/hip_runtime.h>
#include <hip/hip_bf16.h>

#define NN 100000
#define EE 400000
#define GG 4096
#define DD 128
#define ATOM_DIM 101
#define BOND_DIM 11

typedef __attribute__((ext_vector_type(8))) short bf16x8;
typedef __attribute__((ext_vector_type(4))) float f32x4;
typedef __attribute__((ext_vector_type(2))) float f32x2;
typedef __attribute__((ext_vector_type(4))) short short4v;

__device__ __forceinline__ float b2f(short s) {
    unsigned u = ((unsigned)(unsigned short)s) << 16;
    float f; __builtin_memcpy(&f, &u, 4); return f;
}
__device__ __forceinline__ unsigned short f2b(float f) {
    unsigned u; __builtin_memcpy(&u, &f, 4);
    u += 0x7FFFu + ((u >> 16) & 1u);          // RNE
    return (unsigned short)(u >> 16);
}

// ---------------- index dtype detection (int32 vs int64) ----------------
__global__ void detect64_kernel(const void* ei, int npairs, int* flag) {
    const int* p = (const int*)ei;
    int any = 0;
    for (int i = 1; i < 2 * npairs; i += 2) any |= p[i];
    *flag = (any == 0) ? 1 : 0;
}
__device__ __forceinline__ int getIdx(const void* p, long i, int is64) {
    if (is64) return (int)(((const long long*)p)[i]);
    return ((const int*)p)[i];
}

// ---------------- counting sort by dst ----------------
__global__ __launch_bounds__(256) void hist_kernel(
    const void* __restrict__ eidx, const int* __restrict__ flag, int* __restrict__ counts) {
    int e = blockIdx.x * 256 + threadIdx.x;
    if (e >= EE) return;
    int is64 = *flag;
    int dn = getIdx(eidx, (long)EE + e, is64);
    atomicAdd(&counts[dn], 1);
}

__global__ __launch_bounds__(256) void scan1_kernel(
    const int* __restrict__ counts, int* __restrict__ tmp, int* __restrict__ bsum, int n) {
    __shared__ int sd[256];
    const int tid = threadIdx.x;
    int i = blockIdx.x * 256 + tid;
    int v = (i < n) ? counts[i] : 0;
    sd[tid] = v; __syncthreads();
    #pragma unroll
    for (int off = 1; off < 256; off <<= 1) {
        int a = (tid >= off) ? sd[tid - off] : 0;
        __syncthreads();
        sd[tid] += a;
        __syncthreads();
    }
    if (i < n) tmp[i] = sd[tid] - v;          // exclusive
    if (tid == 255) bsum[blockIdx.x] = sd[255];
}

__global__ __launch_bounds__(512) void scan2_kernel(
    const int* __restrict__ bsum, int* __restrict__ bsumx, int nb) {
    __shared__ int sd[512];
    const int tid = threadIdx.x;
    int v = (tid < nb) ? bsum[tid] : 0;
    sd[tid] = v; __syncthreads();
    #pragma unroll
    for (int off = 1; off < 512; off <<= 1) {
        int a = (tid >= off) ? sd[tid - off] : 0;
        __syncthreads();
        sd[tid] += a;
        __syncthreads();
    }
    if (tid < nb) bsumx[tid] = sd[tid] - v;   // exclusive
}

__global__ __launch_bounds__(256) void scan3_kernel(
    const int* __restrict__ tmp, const int* __restrict__ bsumx,
    int* __restrict__ row_ptr, int n) {
    int i = blockIdx.x * 256 + threadIdx.x;
    if (i < n) row_ptr[i] = tmp[i] + bsumx[blockIdx.x];
    if (i == 0) row_ptr[n] = EE;
}

__global__ __launch_bounds__(256) void scatter_kernel(
    const void* __restrict__ eidx, const int* __restrict__ flag,
    const float* __restrict__ ea, const int* __restrict__ row_ptr,
    int* __restrict__ cursor, int* __restrict__ src_sorted, float* __restrict__ eas) {
    int e = blockIdx.x * 256 + threadIdx.x;
    if (e >= EE) return;
    int is64 = *flag;
    int dn = getIdx(eidx, (long)EE + e, is64);
    int sv = getIdx(eidx, e, is64);
    int pos = row_ptr[dn] + atomicAdd(&cursor[dn], 1);
    src_sorted[pos] = sv;
    const float* sp = ea + (long)e * BOND_DIM;
    float* dp = eas + (long)pos * BOND_DIM;
    #pragma unroll
    for (int k = 0; k < BOND_DIM; ++k) dp[k] = sp[k];
}

// ---------------- fused message + aggregate (CSR, no atomics) ----------------
// s[n] = t[n] + sum_{e in N(n)} relu(t[src[e]] + ea[e] @ bw + bb)
__global__ __launch_bounds__(256) void msg_csr_kernel(
    const unsigned short* __restrict__ t,
    const int* __restrict__ src_sorted, const int* __restrict__ row_ptr,
    const float* __restrict__ eas,
    const float* __restrict__ bw,   // [11][128]
    const float* __restrict__ bb,   // [128]
    float* __restrict__ sout)
{
    const int tid = threadIdx.x;
    const int wave = tid >> 6, lane = tid & 63;
    const int d0 = lane * 2;
    float wk0[BOND_DIM], wk1[BOND_DIM];
    #pragma unroll
    for (int k = 0; k < BOND_DIM; ++k) {
        f32x2 wv = *(const f32x2*)(bw + k * DD + d0);
        wk0[k] = wv.x; wk1[k] = wv.y;
    }
    f32x2 bbv = *(const f32x2*)(bb + d0);

    for (int n = blockIdx.x * 4 + wave; n < NN; n += gridDim.x * 4) {
        const int e0 = row_ptr[n], e1 = row_ptr[n + 1];
        float a0 = 0.f, a1 = 0.f;
        for (int e = e0; e < e1; ++e) {
            int sv = src_sorted[e];
            unsigned tv = *(const unsigned*)(t + (long)sv * DD + d0);
            float f0 = b2f((short)(tv & 0xffff));
            float f1 = b2f((short)(tv >> 16));
            const float* ep = eas + (long)e * BOND_DIM;
            float c0 = bbv.x, c1 = bbv.y;
            #pragma unroll
            for (int k = 0; k < BOND_DIM; ++k) {
                float ek = ep[k];
                c0 = fmaf(ek, wk0[k], c0);
                c1 = fmaf(ek, wk1[k], c1);
            }
            a0 += fmaxf(f0 + c0, 0.f);
            a1 += fmaxf(f1 + c1, 0.f);
        }
        unsigned tn = *(const unsigned*)(t + (long)n * DD + d0);
        f32x2 o;
        o.x = b2f((short)(tn & 0xffff)) + a0;
        o.y = b2f((short)(tn >> 16)) + a1;
        *(f32x2*)(sout + (long)n * DD + d0) = o;
    }
}

// ---------------- weight pre-pack: W[K][N] f32 -> Wf[ks][f][lane][8] bf16 ----
__global__ void pack_w(const float* __restrict__ W, unsigned short* __restrict__ Wf,
                       int Kact, int N, int KSTEPS) {
    int idx = blockIdx.x * blockDim.x + threadIdx.x;
    int NF = N >> 4;
    int total = KSTEPS * NF * 64;
    if (idx >= total) return;
    int l = idx & 63;
    int f = (idx >> 6) % NF;
    int ks = idx / (64 * NF);
    int col = f * 16 + (l & 15);
    int k0 = ks * 32 + (l >> 4) * 8;
    bf16x8 v;
    #pragma unroll
    for (int j = 0; j < 8; ++j) {
        int k = k0 + j;
        v[j] = (k < Kact) ? (short)f2b(W[(long)k * N + col]) : (short)0;
    }
    *(bf16x8*)(Wf + (long)idx * 8) = v;
}

// ---------------- x f32 [N,101] -> xb bf16 [N,128] zero-padded ----------------
__global__ void pack_x(const float* __restrict__ x, unsigned short* __restrict__ xb) {
    const long total = (long)NN * 128;
    for (long i = (long)blockIdx.x * blockDim.x + threadIdx.x; i < total;
         i += (long)gridDim.x * blockDim.x) {
        int col = (int)(i & 127);
        long row = i >> 7;
        xb[i] = (col < ATOM_DIM) ? f2b(x[row * ATOM_DIM + col]) : (unsigned short)0;
    }
}

// ---------------- t = bf16(relu(h*sc+sh)) ----------------
__global__ __launch_bounds__(256) void transform_kernel(
    const float* __restrict__ h, const float* __restrict__ sc,
    const float* __restrict__ sh, unsigned short* __restrict__ t) {
    long i = (long)blockIdx.x * blockDim.x + threadIdx.x;
    long base = i * 4;
    if (base >= (long)NN * DD) return;
    int col = (int)(base & 127);
    f32x4 hv = *(const f32x4*)(h + base);
    f32x4 s = *(const f32x4*)(sc + col);
    f32x4 b = *(const f32x4*)(sh + col);
    short4v o;
    o[0] = (short)f2b(fmaxf(hv.x * s.x + b.x, 0.f));
    o[1] = (short)f2b(fmaxf(hv.y * s.y + b.y, 0.f));
    o[2] = (short)f2b(fmaxf(hv.z * s.z + b.z, 0.f));
    o[3] = (short)f2b(fmaxf(hv.w * s.w + b.w, 0.f));
    *(short4v*)(t + base) = o;
}

// ---------------- MFMA GEMM, fused transform + stats ----------------
// MODE 0: A bf16.  MODE 2: bf16 relu(A*sc+sh).  MODE 3: A f32.
template<int NF, int KSTEPS, int MODE, bool OUT_BF16, bool STATS>
__global__ __launch_bounds__(256) void gemm_mfma(
    const void* __restrict__ Ap,
    const float* __restrict__ sc, const float* __restrict__ sh,
    const unsigned short* __restrict__ Wf,  // packed [KSTEPS][NF][64][8]
    const float* __restrict__ bias,         // [NF*16]
    void* __restrict__ outp,
    float* __restrict__ stat,               // [2*NF*16]
    int M)
{
    constexpr int K = KSTEPS * 32;
    constexpr int NC = NF * 16;
    __shared__ float s_sum[NC];
    __shared__ float s_sq[NC];
    const int tid = threadIdx.x;
    const int wave = tid >> 6, l = tid & 63;
    const int r0 = blockIdx.x * 64 + wave * 16;
    const int rr = r0 + (l & 15);
    const int rc = rr < M ? rr : M - 1;
    const int kg = (l >> 4) * 8;

    if (STATS) {
        for (int i = tid; i < NC; i += 256) { s_sum[i] = 0.f; s_sq[i] = 0.f; }
        __syncthreads();
    }

    bf16x8 af[KSTEPS];
    #pragma unroll
    for (int ks = 0; ks < KSTEPS; ++ks) {
        bf16x8 a;
        if (MODE == 3) {
            const float* ap = (const float*)Ap + (long)rc * K + ks * 32 + kg;
            f32x4 v0 = *(const f32x4*)ap, v1 = *(const f32x4*)(ap + 4);
            float vv[8] = {v0.x, v0.y, v0.z, v0.w, v1.x, v1.y, v1.z, v1.w};
            #pragma unroll
            for (int j = 0; j < 8; ++j) a[j] = (short)f2b(vv[j]);
        } else {
            const unsigned short* ap = (const unsigned short*)Ap + (long)rc * K + ks * 32 + kg;
            a = *(const bf16x8*)ap;
            if (MODE == 2) {
                const float* scp = sc + ks * 32 + kg;
                const float* shp = sh + ks * 32 + kg;
                f32x4 s0 = *(const f32x4*)scp, s1 = *(const f32x4*)(scp + 4);
                f32x4 h0 = *(const f32x4*)shp, h1 = *(const f32x4*)(shp + 4);
                float sv[8] = {s0.x, s0.y, s0.z, s0.w, s1.x, s1.y, s1.z, s1.w};
                float hv[8] = {h0.x, h0.y, h0.z, h0.w, h1.x, h1.y, h1.z, h1.w};
                #pragma unroll
                for (int j = 0; j < 8; ++j) {
                    float v = fmaxf(b2f(a[j]) * sv[j] + hv[j], 0.f);
                    a[j] = (short)f2b(v);
                }
            }
        }
        af[ks] = a;
    }

    f32x4 acc[NF];
    #pragma unroll
    for (int f = 0; f < NF; ++f) acc[f] = (f32x4){0.f, 0.f, 0.f, 0.f};

    const bf16x8* wp = (const bf16x8*)Wf;
    #pragma unroll
    for (int ks = 0; ks < KSTEPS; ++ks) {
        #pragma unroll
        for (int f = 0; f < NF; ++f) {
            bf16x8 b = wp[(ks * NF + f) * 64 + l];
            acc[f] = __builtin_amdgcn_mfma_f32_16x16x32_bf16(af[ks], b, acc[f], 0, 0, 0);
        }
    }

    #pragma unroll
    for (int f = 0; f < NF; ++f) {
        const int col = f * 16 + (l & 15);
        const float bb = bias[col];
        float sum = 0.f, sq = 0.f;
        #pragma unroll
        for (int j = 0; j < 4; ++j) {
            int r = r0 + (l >> 4) * 4 + j;
            if (r < M) {
                float v = acc[f][j] + bb;
                if (OUT_BF16) ((unsigned short*)outp)[(long)r * NC + col] = f2b(v);
                else          ((float*)outp)[(long)r * NC + col] = v;
                sum += v; sq += v * v;
            }
        }
        if (STATS) {
            atomicAdd(&s_sum[col], sum);
            atomicAdd(&s_sq[col], sq);
        }
    }
    if (STATS) {
        __syncthreads();
        if (tid < NC) {
            unsafeAtomicAdd(&stat[tid], s_sum[tid]);
            unsafeAtomicAdd(&stat[NC + tid], s_sq[tid]);
        }
    }
}

// ---------------- BN finalize ----------------
__global__ void bn_finalize(const float* __restrict__ stat,
                            const float* __restrict__ gamma, const float* __restrict__ beta,
                            int C, float invN, float* __restrict__ sc, float* __restrict__ sh)
{
    int c = threadIdx.x;
    if (c >= C) return;
    float m = stat[c] * invN;
    float v = stat[C + c] * invN - m * m;
    float s = gamma[c] * rsqrtf(v + 1e-5f);
    sc[c] = s;
    sh[c] = beta[c] - m * s;
}

// ---------------- pooling ----------------
__global__ __launch_bounds__(128) void pool_kernel(
    const float* __restrict__ hraw,
    const float* __restrict__ sc, const float* __restrict__ sh,
    const void* __restrict__ batchp, const int* __restrict__ flag,
    int Nn, float* __restrict__ out)
{
    const int g = blockIdx.x;
    const int t = threadIdx.x;
    const int is64 = *flag;
    int lo = 0, hi = Nn;
    while (lo < hi) { int mid = (lo + hi) >> 1; if (getIdx(batchp, mid, is64) < g) lo = mid + 1; else hi = mid; }
    const int s0 = lo;
    hi = Nn;
    while (lo < hi) { int mid = (lo + hi) >> 1; if (getIdx(batchp, mid, is64) < g + 1) lo = mid + 1; else hi = mid; }
    const int s1 = lo;
    float acc = 0.f;
    for (int r = s0; r < s1; ++r) acc += hraw[(long)r * DD + t];
    const int cnt = s1 - s0;
    float v = 0.f;
    if (cnt > 0) v = (acc / (float)cnt) * sc[t] + sh[t];
    out[(long)g * DD + t] = v;
}

// ---------------- launch ----------------
extern "C" void kernel_launch(void* const* d_in, const int* in_sizes, int n_in,
                              void* d_out, int out_size, void* d_ws, size_t ws_size,
                              hipStream_t stream)
{
    const float* x     = (const float*)d_in[0];
    const float* ea    = (const float*)d_in[1];
    const float* embW  = (const float*)d_in[2];
    const float* embB  = (const float*)d_in[3];
    const float* bondW = (const float*)d_in[4];
    const float* bondB = (const float*)d_in[5];
    const float* W1    = (const float*)d_in[6];
    const float* b1    = (const float*)d_in[7];
    const float* g1    = (const float*)d_in[8];
    const float* be1   = (const float*)d_in[9];
    const float* W2    = (const float*)d_in[10];
    const float* b2    = (const float*)d_in[11];
    const float* gout  = (const float*)d_in[12];
    const float* bout  = (const float*)d_in[13];
    const void*  eidx  = d_in[14];
    const void*  batch = d_in[15];
    float* out = (float*)d_out;

    char* w = (char*)d_ws;
    unsigned short* t   = (unsigned short*)w;   w += (long)NN * DD * 2;        // 25.6MB
    unsigned short* z1  = (unsigned short*)w;   w += (long)NN * 256 * 2;       // 51.2MB
    unsigned short* xb  = z1;   // alias: consumed by emb gemm before z1 written
    float* h    = (float*)w;                    w += (long)NN * DD * 4;        // 51.2MB
    float* s    = h;            // alias: s consumed by gemm1 before gemm2 writes h
    float* eas  = (float*)w;                    w += (long)EE * BOND_DIM * 4;  // 17.6MB
    int* src_sorted = (int*)w;                  w += (long)EE * 4;             // 1.6MB
    int* row_ptr    = (int*)w;                  w += (long)(NN + 1) * 4;
    int* counts     = (int*)w;                  w += (long)NN * 4;
    int* tmp        = (int*)w;                  w += (long)NN * 4;
    int* bsum       = (int*)w;                  w += 1024 * 4;
    int* bsumx      = (int*)w;                  w += 1024 * 4;
    float* stat = (float*)w;                    w += 768 * 4;
    float* sc1  = (float*)w;                    w += 256 * 4;
    float* sh1  = (float*)w;                    w += 256 * 4;
    float* sc2  = (float*)w;                    w += 128 * 4;
    float* sh2  = (float*)w;                    w += 128 * 4;
    unsigned short* embWf = (unsigned short*)w; w += 4 * 8  * 64 * 8 * 2;
    unsigned short* W1f   = (unsigned short*)w; w += 3L * 4 * 16 * 64 * 8 * 2;
    unsigned short* W2f   = (unsigned short*)w; w += 3L * 8 * 8  * 64 * 8 * 2;
    int* flag = (int*)w;

    detect64_kernel<<<1, 1, 0, stream>>>(eidx, 256, flag);

    // pre-pack weights / x
    pack_x<<<4096, 256, 0, stream>>>(x, xb);
    pack_w<<<8, 256, 0, stream>>>(embW, embWf, ATOM_DIM, 128, 4);
    for (int i = 0; i < 3; ++i) {
        pack_w<<<16, 256, 0, stream>>>(W1 + (long)i * 128 * 256, W1f + (long)i * 4 * 16 * 64 * 8, 128, 256, 4);
        pack_w<<<16, 256, 0, stream>>>(W2 + (long)i * 256 * 128, W2f + (long)i * 8 * 8 * 64 * 8, 256, 128, 8);
    }

    // counting sort of edges by dst -> CSR
    const int eblocks = (EE + 255) / 256;
    const int nb = (NN + 255) / 256;   // 391
    hipMemsetAsync(counts, 0, (size_t)NN * 4, stream);
    hist_kernel<<<eblocks, 256, 0, stream>>>(eidx, flag, counts);
    scan1_kernel<<<nb, 256, 0, stream>>>(counts, tmp, bsum, NN);
    scan2_kernel<<<1, 512, 0, stream>>>(bsum, bsumx, nb);
    scan3_kernel<<<nb, 256, 0, stream>>>(tmp, bsumx, row_ptr, NN);
    hipMemsetAsync(counts, 0, (size_t)NN * 4, stream);
    scatter_kernel<<<eblocks, 256, 0, stream>>>(eidx, flag, ea, row_ptr, counts, src_sorted, eas);

    const int gblocks = (NN + 63) / 64;

    // t = bf16(x @ embW + embB)
    gemm_mfma<8, 4, 0, true, false><<<gblocks, 256, 0, stream>>>(
        xb, nullptr, nullptr, embWf, embB, t, nullptr, NN);

    for (int i = 0; i < 3; ++i) {
        // s = t + sum relu(t[src] + bond)   (writes h buffer as s)
        msg_csr_kernel<<<4096, 256, 0, stream>>>(
            t, src_sorted, row_ptr, eas,
            bondW + (long)i * BOND_DIM * DD, bondB + (long)i * DD, s);

        hipMemsetAsync(stat, 0, 768 * sizeof(float), stream);

        // z1 = s @ W1 + b1   [stats -> stat[0:512]]
        gemm_mfma<16, 4, 3, true, true><<<gblocks, 256, 0, stream>>>(
            s, nullptr, nullptr, W1f + (long)i * 4 * 16 * 64 * 8,
            b1 + (long)i * 256, z1, stat, NN);
        bn_finalize<<<1, 256, 0, stream>>>(stat, g1 + (long)i * 256, be1 + (long)i * 256,
                                           256, 1.f / NN, sc1, sh1);

        // h = relu(bn(z1)) @ W2 + b2   [stats -> stat[512:768]]
        gemm_mfma<8, 8, 2, false, true><<<gblocks, 256, 0, stream>>>(
            z1, sc1, sh1, W2f + (long)i * 8 * 8 * 64 * 8,
            b2 + (long)i * DD, h, stat + 512, NN);
        bn_finalize<<<1, 128, 0, stream>>>(stat + 512, gout + (long)i * DD, bout + (long)i * DD,
                                           DD, 1.f / NN, sc2, sh2);

        if (i < 2)
            transform_kernel<<<(int)(((long)NN * DD / 4 + 255) / 256), 256, 0, stream>>>(h, sc2, sh2, t);
    }

    pool_kernel<<<GG, DD, 0, stream>>>(h, sc2, sh2, batch, flag, NN, out);
}

// Round 4
// 894.771 us; speedup vs baseline: 3.6251x; 1.1133x over previous
//
#include <hip/hip_runtime.h>
#include <hip/hip_bf16.h>

#define NN 100000
#define EE 400000
#define GG 4096
#define DD 128
#define ATOM_DIM 101
#define BOND_DIM 11
#define EAP 12   // padded bond-feature stride (48B, 16B-aligned)

typedef __attribute__((ext_vector_type(8))) short bf16x8;
typedef __attribute__((ext_vector_type(4))) float f32x4;
typedef __attribute__((ext_vector_type(2))) float f32x2;
typedef __attribute__((ext_vector_type(4))) short short4v;

__device__ __forceinline__ float b2f(short s) {
    unsigned u = ((unsigned)(unsigned short)s) << 16;
    float f; __builtin_memcpy(&f, &u, 4); return f;
}
__device__ __forceinline__ unsigned short f2b(float f) {
    unsigned u; __builtin_memcpy(&u, &f, 4);
    u += 0x7FFFu + ((u >> 16) & 1u);          // RNE
    return (unsigned short)(u >> 16);
}

// ---------------- index dtype detection (int32 vs int64) ----------------
__global__ void detect64_kernel(const void* ei, int npairs, int* flag) {
    const int* p = (const int*)ei;
    int any = 0;
    for (int i = 1; i < 2 * npairs; i += 2) any |= p[i];
    *flag = (any == 0) ? 1 : 0;
}
__device__ __forceinline__ int getIdx(const void* p, long i, int is64) {
    if (is64) return (int)(((const long long*)p)[i]);
    return ((const int*)p)[i];
}

// ---------------- counting sort by dst ----------------
__global__ __launch_bounds__(256) void hist_kernel(
    const void* __restrict__ eidx, const int* __restrict__ flag, int* __restrict__ counts) {
    int e = blockIdx.x * 256 + threadIdx.x;
    if (e >= EE) return;
    int is64 = *flag;
    int dn = getIdx(eidx, (long)EE + e, is64);
    atomicAdd(&counts[dn], 1);
}

__global__ __launch_bounds__(256) void scan1_kernel(
    const int* __restrict__ counts, int* __restrict__ tmp, int* __restrict__ bsum, int n) {
    __shared__ int sd[256];
    const int tid = threadIdx.x;
    int i = blockIdx.x * 256 + tid;
    int v = (i < n) ? counts[i] : 0;
    sd[tid] = v; __syncthreads();
    #pragma unroll
    for (int off = 1; off < 256; off <<= 1) {
        int a = (tid >= off) ? sd[tid - off] : 0;
        __syncthreads();
        sd[tid] += a;
        __syncthreads();
    }
    if (i < n) tmp[i] = sd[tid] - v;          // exclusive
    if (tid == 255) bsum[blockIdx.x] = sd[255];
}

__global__ __launch_bounds__(512) void scan2_kernel(
    const int* __restrict__ bsum, int* __restrict__ bsumx, int nb) {
    __shared__ int sd[512];
    const int tid = threadIdx.x;
    int v = (tid < nb) ? bsum[tid] : 0;
    sd[tid] = v; __syncthreads();
    #pragma unroll
    for (int off = 1; off < 512; off <<= 1) {
        int a = (tid >= off) ? sd[tid - off] : 0;
        __syncthreads();
        sd[tid] += a;
        __syncthreads();
    }
    if (tid < nb) bsumx[tid] = sd[tid] - v;   // exclusive
}

__global__ __launch_bounds__(256) void scan3_kernel(
    const int* __restrict__ tmp, const int* __restrict__ bsumx,
    int* __restrict__ row_ptr, int n) {
    int i = blockIdx.x * 256 + threadIdx.x;
    if (i < n) row_ptr[i] = tmp[i] + bsumx[blockIdx.x];
    if (i == 0) row_ptr[n] = EE;
}

__global__ __launch_bounds__(256) void scatter_kernel(
    const void* __restrict__ eidx, const int* __restrict__ flag,
    const float* __restrict__ ea, const int* __restrict__ row_ptr,
    int* __restrict__ cursor, int* __restrict__ src_sorted, float* __restrict__ eas) {
    int e = blockIdx.x * 256 + threadIdx.x;
    if (e >= EE) return;
    int is64 = *flag;
    int dn = getIdx(eidx, (long)EE + e, is64);
    int sv = getIdx(eidx, e, is64);
    int pos = row_ptr[dn] + atomicAdd(&cursor[dn], 1);
    src_sorted[pos] = sv;
    const float* sp = ea + (long)e * BOND_DIM;
    float* dp = eas + (long)pos * EAP;
    #pragma unroll
    for (int k = 0; k < BOND_DIM; ++k) dp[k] = sp[k];
    dp[11] = 0.f;
}

// ---------------- fused message + aggregate (CSR, no atomics) ----------------
// s[n] = t[n] + sum_{e in N(n)} relu(t[src[e]] + ea[e] @ bw + bb)
__global__ __launch_bounds__(256) void msg_csr_kernel(
    const unsigned short* __restrict__ t,
    const int* __restrict__ src_sorted, const int* __restrict__ row_ptr,
    const float* __restrict__ eas,
    const float* __restrict__ bw,   // [11][128]
    const float* __restrict__ bb,   // [128]
    float* __restrict__ sout)
{
    const int tid = threadIdx.x;
    const int wave = tid >> 6, lane = tid & 63;
    const int d0 = lane * 2;
    float wk0[BOND_DIM], wk1[BOND_DIM];
    #pragma unroll
    for (int k = 0; k < BOND_DIM; ++k) {
        f32x2 wv = *(const f32x2*)(bw + k * DD + d0);
        wk0[k] = wv.x; wk1[k] = wv.y;
    }
    f32x2 bbv = *(const f32x2*)(bb + d0);

    for (int n = blockIdx.x * 4 + wave; n < NN; n += gridDim.x * 4) {
        const int e0 = row_ptr[n], e1 = row_ptr[n + 1];
        float a0 = 0.f, a1 = 0.f;
        for (int e = e0; e < e1; ++e) {
            int sv = src_sorted[e];
            unsigned tv = *(const unsigned*)(t + (long)sv * DD + d0);
            float f0 = b2f((short)(tv & 0xffff));
            float f1 = b2f((short)(tv >> 16));
            const float* ep = eas + (long)e * EAP;
            f32x4 ev0 = *(const f32x4*)ep;
            f32x4 ev1 = *(const f32x4*)(ep + 4);
            f32x4 ev2 = *(const f32x4*)(ep + 8);
            float ev[12] = {ev0.x, ev0.y, ev0.z, ev0.w,
                            ev1.x, ev1.y, ev1.z, ev1.w,
                            ev2.x, ev2.y, ev2.z, ev2.w};
            float c0 = bbv.x, c1 = bbv.y;
            #pragma unroll
            for (int k = 0; k < BOND_DIM; ++k) {
                c0 = fmaf(ev[k], wk0[k], c0);
                c1 = fmaf(ev[k], wk1[k], c1);
            }
            a0 += fmaxf(f0 + c0, 0.f);
            a1 += fmaxf(f1 + c1, 0.f);
        }
        unsigned tn = *(const unsigned*)(t + (long)n * DD + d0);
        f32x2 o;
        o.x = b2f((short)(tn & 0xffff)) + a0;
        o.y = b2f((short)(tn >> 16)) + a1;
        *(f32x2*)(sout + (long)n * DD + d0) = o;
    }
}

// ---------------- weight pre-pack: W[K][N] f32 -> Wf[ks][f][lane][8] bf16 ----
__global__ void pack_w(const float* __restrict__ W, unsigned short* __restrict__ Wf,
                       int Kact, int N, int KSTEPS) {
    int idx = blockIdx.x * blockDim.x + threadIdx.x;
    int NF = N >> 4;
    int total = KSTEPS * NF * 64;
    if (idx >= total) return;
    int l = idx & 63;
    int f = (idx >> 6) % NF;
    int ks = idx / (64 * NF);
    int col = f * 16 + (l & 15);
    int k0 = ks * 32 + (l >> 4) * 8;
    bf16x8 v;
    #pragma unroll
    for (int j = 0; j < 8; ++j) {
        int k = k0 + j;
        v[j] = (k < Kact) ? (short)f2b(W[(long)k * N + col]) : (short)0;
    }
    *(bf16x8*)(Wf + (long)idx * 8) = v;
}

// ---------------- x f32 [N,101] -> xb bf16 [N,128] zero-padded ----------------
__global__ void pack_x(const float* __restrict__ x, unsigned short* __restrict__ xb) {
    const long total = (long)NN * 128;
    for (long i = (long)blockIdx.x * blockDim.x + threadIdx.x; i < total;
         i += (long)gridDim.x * blockDim.x) {
        int col = (int)(i & 127);
        long row = i >> 7;
        xb[i] = (col < ATOM_DIM) ? f2b(x[row * ATOM_DIM + col]) : (unsigned short)0;
    }
}

// ---------------- t = bf16(relu(h*sc+sh)) ----------------
__global__ __launch_bounds__(256) void transform_kernel(
    const float* __restrict__ h, const float* __restrict__ sc,
    const float* __restrict__ sh, unsigned short* __restrict__ t) {
    long i = (long)blockIdx.x * blockDim.x + threadIdx.x;
    long base = i * 4;
    if (base >= (long)NN * DD) return;
    int col = (int)(base & 127);
    f32x4 hv = *(const f32x4*)(h + base);
    f32x4 s = *(const f32x4*)(sc + col);
    f32x4 b = *(const f32x4*)(sh + col);
    short4v o;
    o[0] = (short)f2b(fmaxf(hv.x * s.x + b.x, 0.f));
    o[1] = (short)f2b(fmaxf(hv.y * s.y + b.y, 0.f));
    o[2] = (short)f2b(fmaxf(hv.z * s.z + b.z, 0.f));
    o[3] = (short)f2b(fmaxf(hv.w * s.w + b.w, 0.f));
    *(short4v*)(t + base) = o;
}

// ---------------- MFMA GEMM, LDS-staged B, fused transform + stats ----------------
// MODE 0: A bf16.  MODE 2: bf16 relu(A*sc+sh).  MODE 3: A f32.
template<int NF, int KSTEPS, int MODE, bool OUT_BF16, bool STATS>
__global__ __launch_bounds__(256) void gemm_mfma(
    const void* __restrict__ Ap,
    const float* __restrict__ sc, const float* __restrict__ sh,
    const unsigned short* __restrict__ Wf,  // packed [KSTEPS][NF][64][8]
    const float* __restrict__ bias,         // [NF*16]
    void* __restrict__ outp,
    float* __restrict__ stat,               // [2*NF*16]
    int M)
{
    constexpr int K = KSTEPS * 32;
    constexpr int NC = NF * 16;
    constexpr int HALF = KSTEPS / 2;              // ks per pass (2 passes)
    constexpr int UNITS = HALF * NF * 64;         // 16B units per pass (<= 2048 = 32KB)
    constexpr int SLOADS = UNITS / 256;           // 16B loads per thread per pass

    __shared__ __align__(16) unsigned short sB[UNITS * 8];
    __shared__ float s_sum[NC];
    __shared__ float s_sq[NC];

    const int tid = threadIdx.x;
    const int wave = tid >> 6, l = tid & 63;
    const int r0 = blockIdx.x * 64 + wave * 16;
    const int rr = r0 + (l & 15);
    const int rc = rr < M ? rr : M - 1;
    const int kg = (l >> 4) * 8;

    const bf16x8* gW = (const bf16x8*)Wf;
    bf16x8* sB8 = (bf16x8*)sB;

    // issue pass-0 B staging loads
    bf16x8 stg[SLOADS];
    #pragma unroll
    for (int i = 0; i < SLOADS; ++i) stg[i] = gW[i * 256 + tid];

    if (STATS) {
        for (int i = tid; i < NC; i += 256) { s_sum[i] = 0.f; s_sq[i] = 0.f; }
    }

    // A fragments (overlaps staging latency)
    bf16x8 af[KSTEPS];
    #pragma unroll
    for (int ks = 0; ks < KSTEPS; ++ks) {
        bf16x8 a;
        if (MODE == 3) {
            const float* ap = (const float*)Ap + (long)rc * K + ks * 32 + kg;
            f32x4 v0 = *(const f32x4*)ap, v1 = *(const f32x4*)(ap + 4);
            float vv[8] = {v0.x, v0.y, v0.z, v0.w, v1.x, v1.y, v1.z, v1.w};
            #pragma unroll
            for (int j = 0; j < 8; ++j) a[j] = (short)f2b(vv[j]);
        } else {
            const unsigned short* ap = (const unsigned short*)Ap + (long)rc * K + ks * 32 + kg;
            a = *(const bf16x8*)ap;
            if (MODE == 2) {
                const float* scp = sc + ks * 32 + kg;
                const float* shp = sh + ks * 32 + kg;
                f32x4 s0 = *(const f32x4*)scp, s1 = *(const f32x4*)(scp + 4);
                f32x4 h0 = *(const f32x4*)shp, h1 = *(const f32x4*)(shp + 4);
                float sv[8] = {s0.x, s0.y, s0.z, s0.w, s1.x, s1.y, s1.z, s1.w};
                float hv[8] = {h0.x, h0.y, h0.z, h0.w, h1.x, h1.y, h1.z, h1.w};
                #pragma unroll
                for (int j = 0; j < 8; ++j) {
                    float v = fmaxf(b2f(a[j]) * sv[j] + hv[j], 0.f);
                    a[j] = (short)f2b(v);
                }
            }
        }
        af[ks] = a;
    }

    f32x4 acc[NF];
    #pragma unroll
    for (int f = 0; f < NF; ++f) acc[f] = (f32x4){0.f, 0.f, 0.f, 0.f};

    // write pass-0 B to LDS
    #pragma unroll
    for (int i = 0; i < SLOADS; ++i) sB8[i * 256 + tid] = stg[i];
    __syncthreads();

    #pragma unroll
    for (int p = 0; p < 2; ++p) {
        if (p == 0) {
            // issue pass-1 staging loads; they fly during pass-0 MFMAs
            #pragma unroll
            for (int i = 0; i < SLOADS; ++i) stg[i] = gW[UNITS + i * 256 + tid];
        }
        #pragma unroll
        for (int ksl = 0; ksl < HALF; ++ksl) {
            #pragma unroll
            for (int f = 0; f < NF; ++f) {
                bf16x8 b = sB8[(ksl * NF + f) * 64 + l];
                acc[f] = __builtin_amdgcn_mfma_f32_16x16x32_bf16(af[p * HALF + ksl], b, acc[f], 0, 0, 0);
            }
        }
        if (p == 0) {
            __syncthreads();   // everyone done reading pass-0 LDS
            #pragma unroll
            for (int i = 0; i < SLOADS; ++i) sB8[i * 256 + tid] = stg[i];
            __syncthreads();
        }
    }

    #pragma unroll
    for (int f = 0; f < NF; ++f) {
        const int col = f * 16 + (l & 15);
        const float bb = bias[col];
        float sum = 0.f, sq = 0.f;
        #pragma unroll
        for (int j = 0; j < 4; ++j) {
            int r = r0 + (l >> 4) * 4 + j;
            if (r < M) {
                float v = acc[f][j] + bb;
                if (OUT_BF16) ((unsigned short*)outp)[(long)r * NC + col] = f2b(v);
                else          ((float*)outp)[(long)r * NC + col] = v;
                sum += v; sq += v * v;
            }
        }
        if (STATS) {
            sum += __shfl_xor(sum, 16);
            sum += __shfl_xor(sum, 32);
            sq  += __shfl_xor(sq, 16);
            sq  += __shfl_xor(sq, 32);
            if (l < 16) {
                atomicAdd(&s_sum[col], sum);
                atomicAdd(&s_sq[col], sq);
            }
        }
    }
    if (STATS) {
        __syncthreads();
        if (tid < NC) {
            unsafeAtomicAdd(&stat[tid], s_sum[tid]);
            unsafeAtomicAdd(&stat[NC + tid], s_sq[tid]);
        }
    }
}

// ---------------- BN finalize ----------------
__global__ void bn_finalize(const float* __restrict__ stat,
                            const float* __restrict__ gamma, const float* __restrict__ beta,
                            int C, float invN, float* __restrict__ sc, float* __restrict__ sh)
{
    int c = threadIdx.x;
    if (c >= C) return;
    float m = stat[c] * invN;
    float v = stat[C + c] * invN - m * m;
    float s = gamma[c] * rsqrtf(v + 1e-5f);
    sc[c] = s;
    sh[c] = beta[c] - m * s;
}

// ---------------- pooling ----------------
__global__ __launch_bounds__(128) void pool_kernel(
    const float* __restrict__ hraw,
    const float* __restrict__ sc, const float* __restrict__ sh,
    const void* __restrict__ batchp, const int* __restrict__ flag,
    int Nn, float* __restrict__ out)
{
    const int g = blockIdx.x;
    const int t = threadIdx.x;
    const int is64 = *flag;
    int lo = 0, hi = Nn;
    while (lo < hi) { int mid = (lo + hi) >> 1; if (getIdx(batchp, mid, is64) < g) lo = mid + 1; else hi = mid; }
    const int s0 = lo;
    hi = Nn;
    while (lo < hi) { int mid = (lo + hi) >> 1; if (getIdx(batchp, mid, is64) < g + 1) lo = mid + 1; else hi = mid; }
    const int s1 = lo;
    float acc = 0.f;
    for (int r = s0; r < s1; ++r) acc += hraw[(long)r * DD + t];
    const int cnt = s1 - s0;
    float v = 0.f;
    if (cnt > 0) v = (acc / (float)cnt) * sc[t] + sh[t];
    out[(long)g * DD + t] = v;
}

// ---------------- launch ----------------
extern "C" void kernel_launch(void* const* d_in, const int* in_sizes, int n_in,
                              void* d_out, int out_size, void* d_ws, size_t ws_size,
                              hipStream_t stream)
{
    const float* x     = (const float*)d_in[0];
    const float* ea    = (const float*)d_in[1];
    const float* embW  = (const float*)d_in[2];
    const float* embB  = (const float*)d_in[3];
    const float* bondW = (const float*)d_in[4];
    const float* bondB = (const float*)d_in[5];
    const float* W1    = (const float*)d_in[6];
    const float* b1    = (const float*)d_in[7];
    const float* g1    = (const float*)d_in[8];
    const float* be1   = (const float*)d_in[9];
    const float* W2    = (const float*)d_in[10];
    const float* b2    = (const float*)d_in[11];
    const float* gout  = (const float*)d_in[12];
    const float* bout  = (const float*)d_in[13];
    const void*  eidx  = d_in[14];
    const void*  batch = d_in[15];
    float* out = (float*)d_out;

    char* w = (char*)d_ws;
    unsigned short* t   = (unsigned short*)w;   w += (long)NN * DD * 2;        // 25.6MB
    unsigned short* z1  = (unsigned short*)w;   w += (long)NN * 256 * 2;       // 51.2MB
    unsigned short* xb  = z1;   // alias: consumed by emb gemm before z1 written
    float* h    = (float*)w;                    w += (long)NN * DD * 4;        // 51.2MB
    float* s    = h;            // alias: s consumed by gemm1 before gemm2 writes h
    float* eas  = (float*)w;                    w += (long)EE * EAP * 4;       // 19.2MB
    int* src_sorted = (int*)w;                  w += (long)EE * 4;             // 1.6MB
    int* row_ptr    = (int*)w;                  w += (long)(NN + 1) * 4;
    int* counts     = (int*)w;                  w += (long)NN * 4;
    int* tmp        = (int*)w;                  w += (long)NN * 4;
    int* bsum       = (int*)w;                  w += 1024 * 4;
    int* bsumx      = (int*)w;                  w += 1024 * 4;
    float* stat = (float*)w;                    w += 768 * 4;
    float* sc1  = (float*)w;                    w += 256 * 4;
    float* sh1  = (float*)w;                    w += 256 * 4;
    float* sc2  = (float*)w;                    w += 128 * 4;
    float* sh2  = (float*)w;                    w += 128 * 4;
    unsigned short* embWf = (unsigned short*)w; w += 4 * 8  * 64 * 8 * 2;
    unsigned short* W1f   = (unsigned short*)w; w += 3L * 4 * 16 * 64 * 8 * 2;
    unsigned short* W2f   = (unsigned short*)w; w += 3L * 8 * 8  * 64 * 8 * 2;
    int* flag = (int*)w;

    detect64_kernel<<<1, 1, 0, stream>>>(eidx, 256, flag);

    // pre-pack weights / x
    pack_x<<<4096, 256, 0, stream>>>(x, xb);
    pack_w<<<8, 256, 0, stream>>>(embW, embWf, ATOM_DIM, 128, 4);
    for (int i = 0; i < 3; ++i) {
        pack_w<<<16, 256, 0, stream>>>(W1 + (long)i * 128 * 256, W1f + (long)i * 4 * 16 * 64 * 8, 128, 256, 4);
        pack_w<<<16, 256, 0, stream>>>(W2 + (long)i * 256 * 128, W2f + (long)i * 8 * 8 * 64 * 8, 256, 128, 8);
    }

    // counting sort of edges by dst -> CSR
    const int eblocks = (EE + 255) / 256;
    const int nb = (NN + 255) / 256;   // 391
    hipMemsetAsync(counts, 0, (size_t)NN * 4, stream);
    hist_kernel<<<eblocks, 256, 0, stream>>>(eidx, flag, counts);
    scan1_kernel<<<nb, 256, 0, stream>>>(counts, tmp, bsum, NN);
    scan2_kernel<<<1, 512, 0, stream>>>(bsum, bsumx, nb);
    scan3_kernel<<<nb, 256, 0, stream>>>(tmp, bsumx, row_ptr, NN);
    hipMemsetAsync(counts, 0, (size_t)NN * 4, stream);
    scatter_kernel<<<eblocks, 256, 0, stream>>>(eidx, flag, ea, row_ptr, counts, src_sorted, eas);

    const int gblocks = (NN + 63) / 64;

    // t = bf16(x @ embW + embB)
    gemm_mfma<8, 4, 0, true, false><<<gblocks, 256, 0, stream>>>(
        xb, nullptr, nullptr, embWf, embB, t, nullptr, NN);

    for (int i = 0; i < 3; ++i) {
        // s = t + sum relu(t[src] + bond)   (writes h buffer as s)
        msg_csr_kernel<<<4096, 256, 0, stream>>>(
            t, src_sorted, row_ptr, eas,
            bondW + (long)i * BOND_DIM * DD, bondB + (long)i * DD, s);

        hipMemsetAsync(stat, 0, 768 * sizeof(float), stream);

        // z1 = s @ W1 + b1   [stats -> stat[0:512]]
        gemm_mfma<16, 4, 3, true, true><<<gblocks, 256, 0, stream>>>(
            s, nullptr, nullptr, W1f + (long)i * 4 * 16 * 64 * 8,
            b1 + (long)i * 256, z1, stat, NN);
        bn_finalize<<<1, 256, 0, stream>>>(stat, g1 + (long)i * 256, be1 + (long)i * 256,
                                           256, 1.f / NN, sc1, sh1);

        // h = relu(bn(z1)) @ W2 + b2   [stats -> stat[512:768]]
        gemm_mfma<8, 8, 2, false, true><<<gblocks, 256, 0, stream>>>(
            z1, sc1, sh1, W2f + (long)i * 8 * 8 * 64 * 8,
            b2 + (long)i * DD, h, stat + 512, NN);
        bn_finalize<<<1, 128, 0, stream>>>(stat + 512, gout + (long)i * DD, bout + (long)i * DD,
                                           DD, 1.f / NN, sc2, sh2);

        if (i < 2)
            transform_kernel<<<(int)(((long)NN * DD / 4 + 255) / 256), 256, 0, stream>>>(h, sc2, sh2, t);
    }

    pool_kernel<<<GG, DD, 0, stream>>>(h, sc2, sh2, batch, flag, NN, out);
}